// Round 1
// baseline (626.855 us; speedup 1.0000x reference)
//
#include <hip/hip_runtime.h>
#include <math.h>

typedef int      v4i __attribute__((ext_vector_type(4)));
typedef unsigned v4u __attribute__((ext_vector_type(4)));
typedef float    v4f __attribute__((ext_vector_type(4)));

#define T_TOK 16384
#define H_DIM 4096
#define E_EXP 256

// ---------------------------------------------------------------------------
// Limb conversion: fp32 -> 4 planes of signed-char balanced base-256 limbs.
// v = round(x*scale), v = l0 + l1*256 + l2*65536 + l3*16777216, l in [-128,127].
// A: scale 2^28 (|x|<7.99 safe); B: scale 2^36 (|b|<2^-6 -> v<2^30).
// ---------------------------------------------------------------------------
__global__ __launch_bounds__(256) void k_conv(const float* __restrict__ x,
                                              signed char* __restrict__ planes,
                                              long n, float scale) {
  long g = (long)blockIdx.x * 256 + threadIdx.x;
  long base = g * 16;
  const v4f* src = (const v4f*)(x + base);
  v4f f0 = src[0], f1 = src[1], f2 = src[2], f3 = src[3];
  float xs[16];
#pragma unroll
  for (int i = 0; i < 4; i++) { xs[i] = f0[i]; xs[4+i] = f1[i]; xs[8+i] = f2[i]; xs[12+i] = f3[i]; }
  unsigned pk[4][4];
#pragma unroll
  for (int p = 0; p < 4; p++)
#pragma unroll
    for (int wd = 0; wd < 4; wd++) pk[p][wd] = 0u;
#pragma unroll
  for (int e = 0; e < 16; e++) {
    int v = __float2int_rn(xs[e] * scale);
    int l0 = ((v + 128) & 255) - 128; v = (v - l0) >> 8;
    int l1 = ((v + 128) & 255) - 128; v = (v - l1) >> 8;
    int l2 = ((v + 128) & 255) - 128; v = (v - l2) >> 8;
    int sh = (e & 3) * 8, wd = e >> 2;
    pk[0][wd] |= (unsigned)(l0 & 255) << sh;
    pk[1][wd] |= (unsigned)(l1 & 255) << sh;
    pk[2][wd] |= (unsigned)(l2 & 255) << sh;
    pk[3][wd] |= (unsigned)(v  & 255) << sh;
  }
#pragma unroll
  for (int p = 0; p < 4; p++) {
    v4u o = { pk[p][0], pk[p][1], pk[p][2], pk[p][3] };
    *(v4u*)(planes + (long)p * n + base) = o;
  }
}

// ---------------------------------------------------------------------------
// Exact-int i8 MFMA GEMM: logits[t][e] = hidden[t][:] . weight[e][:]
// Tile: BM=64, BN=128, BK=64. 256 threads = 4 waves, wave tile 64x32.
// 10 limb-pair products in 4 i32 accumulator groups (pair weights 2^-16..2^-40).
// LDS rows padded to 80B -> 2-way bank aliasing only (free).
// ---------------------------------------------------------------------------
#define LA    80
#define A_PL  5120    // 64*80
#define B_PL  10240   // 128*80
#define B_BASE 20480  // 4*A_PL

#define MFMA(a,b,c) __builtin_amdgcn_mfma_i32_16x16x64_i8((a),(b),(c),0,0,0)

__global__ __launch_bounds__(256, 2) void k_gemm(const signed char* __restrict__ Ap,
                                                 const signed char* __restrict__ Bp,
                                                 double* __restrict__ logits) {
  __shared__ __align__(16) signed char lds[61440];
  const long AH = (long)T_TOK * H_DIM, BH = (long)E_EXP * H_DIM;
  int tid = threadIdx.x;
  int mt = blockIdx.x >> 1, nt = blockIdx.x & 1;
  int w = tid >> 6, lane = tid & 63;
  int sr = tid >> 2, sc = (tid & 3) << 4;

  const signed char* aSrc = Ap + (long)(mt * 64 + sr) * H_DIM + sc;
  const signed char* bSrc = Bp + (long)(nt * 128) * H_DIM + sc;

  int row = lane & 15, kq = lane >> 4;
  int aoff = row * LA + kq * 16;
  int boff = B_BASE + (w * 32 + row) * LA + kq * 16;

  v4i ar[4], br[8];
  v4i zero = {0, 0, 0, 0};
  v4i acc[4][2][4];
#pragma unroll
  for (int f = 0; f < 4; f++)
#pragma unroll
    for (int nn = 0; nn < 2; nn++)
#pragma unroll
      for (int s = 0; s < 4; s++) acc[f][nn][s] = zero;

#define LOAD_TILES(KT) do {                                                   \
    int koff = (KT) << 6;                                                     \
    _Pragma("unroll")                                                         \
    for (int p = 0; p < 4; p++)                                               \
      ar[p] = *(const v4i*)(aSrc + (long)p * AH + koff);                      \
    _Pragma("unroll")                                                         \
    for (int j = 0; j < 8; j++) {                                             \
      int p = j >> 1; int r = ((j & 1) << 6) + sr;                            \
      br[j] = *(const v4i*)(bSrc + (long)p * BH + (long)r * H_DIM + koff);    \
    }                                                                         \
  } while (0)

  LOAD_TILES(0);

#pragma unroll 1
  for (int kt = 0; kt < H_DIM / 64; ++kt) {
    __syncthreads();
#pragma unroll
    for (int p = 0; p < 4; p++)
      *(v4i*)(lds + p * A_PL + sr * LA + sc) = ar[p];
#pragma unroll
    for (int j = 0; j < 8; j++) {
      int p = j >> 1; int r = ((j & 1) << 6) + sr;
      *(v4i*)(lds + B_BASE + p * B_PL + r * LA + sc) = br[j];
    }
    __syncthreads();

    v4i af[4][4];
#pragma unroll
    for (int f = 0; f < 4; f++)
#pragma unroll
      for (int p = 0; p < 4; p++)
        af[f][p] = *(const v4i*)(lds + p * A_PL + f * (16 * LA) + aoff);

#pragma unroll
    for (int nn = 0; nn < 2; nn++) {
      v4i bf[4];
#pragma unroll
      for (int p = 0; p < 4; p++)
        bf[p] = *(const v4i*)(lds + p * B_PL + nn * (16 * LA) + boff);
#pragma unroll
      for (int f = 0; f < 4; f++) {
        acc[f][nn][0] = MFMA(af[f][3], bf[3], acc[f][nn][0]);           // s=6  w 2^-16
        acc[f][nn][1] = MFMA(af[f][2], bf[3], acc[f][nn][1]);           // s=5  w 2^-24
        acc[f][nn][1] = MFMA(af[f][3], bf[2], acc[f][nn][1]);
        acc[f][nn][2] = MFMA(af[f][1], bf[3], acc[f][nn][2]);           // s=4  w 2^-32
        acc[f][nn][2] = MFMA(af[f][2], bf[2], acc[f][nn][2]);
        acc[f][nn][2] = MFMA(af[f][3], bf[1], acc[f][nn][2]);
        acc[f][nn][3] = MFMA(af[f][0], bf[3], acc[f][nn][3]);           // s=3  w 2^-40
        acc[f][nn][3] = MFMA(af[f][1], bf[2], acc[f][nn][3]);
        acc[f][nn][3] = MFMA(af[f][2], bf[1], acc[f][nn][3]);
        acc[f][nn][3] = MFMA(af[f][3], bf[0], acc[f][nn][3]);
      }
    }
    if (kt < H_DIM / 64 - 1) LOAD_TILES(kt + 1);
  }

#pragma unroll
  for (int f = 0; f < 4; f++)
#pragma unroll
    for (int nn = 0; nn < 2; nn++) {
      int col = nt * 128 + w * 32 + nn * 16 + row;
#pragma unroll
      for (int r4 = 0; r4 < 4; r4++) {
        int rowg = mt * 64 + f * 16 + kq * 4 + r4;
        double d = (double)acc[f][nn][0][r4] * 0x1p-16
                 + (double)acc[f][nn][1][r4] * 0x1p-24
                 + (double)acc[f][nn][2][r4] * 0x1p-32
                 + (double)acc[f][nn][3][r4] * 0x1p-40;
        logits[(long)rowg * E_EXP + col] = d;
      }
    }
}

// ---------------------------------------------------------------------------
// Routing: one wave per token. f64 sigmoid/bias, group-limited top-k with
// jax.lax.top_k semantics (descending, ties -> lower index).
// lane holds experts [lane*4, lane*4+4); group g = lane>>3 (8 lanes/group).
// ---------------------------------------------------------------------------
__global__ __launch_bounds__(256) void k_route(const double* __restrict__ logits,
                                               const float* __restrict__ bias,
                                               float* __restrict__ out) {
  int w = threadIdx.x >> 6, lane = threadIdx.x & 63;
  int t = blockIdx.x * 4 + w;
  const double* lg = logits + (long)t * E_EXP + lane * 4;
  double x0 = lg[0], x1 = lg[1], x2 = lg[2], x3 = lg[3];
  double s0 = 1.0 / (1.0 + exp(-x0));
  double s1 = 1.0 / (1.0 + exp(-x1));
  double s2 = 1.0 / (1.0 + exp(-x2));
  double s3 = 1.0 / (1.0 + exp(-x3));
  int e0 = lane << 2;
  double r0 = s0 + (double)bias[e0];
  double r1 = s1 + (double)bias[e0 + 1];
  double r2 = s2 + (double)bias[e0 + 2];
  double r3 = s3 + (double)bias[e0 + 3];

  // top-2 of my 4 (values only)
  double hi1 = fmax(r0, r1), lo1 = fmin(r0, r1);
  double hi2 = fmax(r2, r3), lo2 = fmin(r2, r3);
  double m1 = fmax(hi1, hi2);
  double m2 = fmax(fmin(hi1, hi2), fmax(lo1, lo2));
  // butterfly top-2 merge across the 8 lanes of my group
#pragma unroll
  for (int k = 1; k < 8; k <<= 1) {
    double o1 = __shfl_xor(m1, k), o2 = __shfl_xor(m2, k);
    double n1 = fmax(m1, o1);
    double n2 = fmax(fmin(m1, o1), fmax(m2, o2));
    m1 = n1; m2 = n2;
  }
  double gsc = m1 + m2;
  int g = lane >> 3;
  int cnt = 0;
#pragma unroll
  for (int j = 0; j < 8; j++) {
    double gj = __shfl(gsc, j * 8);
    cnt += (gj > gsc || (gj == gsc && j < g)) ? 1 : 0;
  }
  bool sel = cnt < 4;
  double NEG = -INFINITY;
  double M0 = sel ? r0 : NEG;
  double M1 = sel ? r1 : NEG;
  double M2 = sel ? r2 : NEG;
  double M3 = sel ? r3 : NEG;

  double wsum = 0.0;
  double wv[8]; int wi[8];
#pragma unroll
  for (int it = 0; it < 8; it++) {
    double bv = M0; int bi = e0;
    if (M1 > bv) { bv = M1; bi = e0 + 1; }
    if (M2 > bv) { bv = M2; bi = e0 + 2; }
    if (M3 > bv) { bv = M3; bi = e0 + 3; }
#pragma unroll
    for (int k = 1; k < 64; k <<= 1) {
      double ov = __shfl_xor(bv, k); int oi = __shfl_xor(bi, k);
      if (ov > bv || (ov == bv && oi < bi)) { bv = ov; bi = oi; }
    }
    int q = bi & 3, src = bi >> 2;
    double mys = (q == 0) ? s0 : (q == 1) ? s1 : (q == 2) ? s2 : s3;
    double sv = __shfl(mys, src);
    wv[it] = sv; wi[it] = bi; wsum += sv;
    if (lane == src) {
      if (q == 0) M0 = NEG; else if (q == 1) M1 = NEG;
      else if (q == 2) M2 = NEG; else M3 = NEG;
    }
  }
  if (lane == 0) {
    double invs = 2.5 / (wsum + 1e-20);
#pragma unroll
    for (int it = 0; it < 8; it++) {
      out[(long)t * 8 + it] = (float)(wv[it] * invs);
      out[(long)T_TOK * 8 + (long)t * 8 + it] = (float)wi[it];
    }
  }
}

// ---------------------------------------------------------------------------
extern "C" void kernel_launch(void* const* d_in, const int* in_sizes, int n_in,
                              void* d_out, int out_size, void* d_ws, size_t ws_size,
                              hipStream_t stream) {
  const float* hidden = (const float*)d_in[0];
  const float* weight = (const float*)d_in[1];
  const float* bias   = (const float*)d_in[2];
  float* out = (float*)d_out;

  size_t a_bytes = (size_t)4 * T_TOK * H_DIM;   // 268,435,456
  size_t b_bytes = (size_t)4 * E_EXP * H_DIM;   //   4,194,304
  size_t l_bytes = (size_t)T_TOK * E_EXP * 8;   //  33,554,432
  if (ws_size < a_bytes + b_bytes + l_bytes) return;  // insufficient scratch

  signed char* Ap = (signed char*)d_ws;
  signed char* Bp = Ap + a_bytes;
  double* logits = (double*)(Bp + b_bytes);

  hipLaunchKernelGGL(k_conv, dim3(((long)T_TOK * H_DIM) / 16 / 256), dim3(256), 0, stream,
                     hidden, Ap, (long)T_TOK * H_DIM, 268435456.0f /* 2^28 */);
  hipLaunchKernelGGL(k_conv, dim3(((long)E_EXP * H_DIM) / 16 / 256), dim3(256), 0, stream,
                     weight, Bp, (long)E_EXP * H_DIM, 68719476736.0f /* 2^36 */);
  hipLaunchKernelGGL(k_gemm, dim3((T_TOK / 64) * (E_EXP / 128)), dim3(256), 0, stream,
                     Ap, Bp, logits);
  hipLaunchKernelGGL(k_route, dim3(T_TOK / 4), dim3(256), 0, stream, logits, bias, out);
}